// Round 7
// baseline (397.163 us; speedup 1.0000x reference)
//
#include <hip/hip_runtime.h>
#include <cstdint>
#include <cstddef>

// Problem constants
constexpr int B_   = 4;
constexpr int SEQ  = 2048;
constexpr int E    = 1024;   // embed dim
constexpr int KVE  = 512;    // kv embed dim
constexpr int H    = 4;      // kv heads
constexpr int ROWS = B_ * SEQ;   // 8192 tokens
constexpr int NSPLIT = 2;        // KV split
constexpr int KVT  = SEQ / NSPLIT;  // 1024 keys per block
constexpr int NT   = KVT / 64;      // 16 tiles of 64 keys

typedef short short8   __attribute__((ext_vector_type(8)));
typedef short short4v  __attribute__((ext_vector_type(4)));
typedef float floatx4  __attribute__((ext_vector_type(4)));
typedef float floatx16 __attribute__((ext_vector_type(16)));
typedef int   intx4    __attribute__((ext_vector_type(4)));

__device__ inline short f2bf(float f) {   // RNE float->bf16
    uint32_t u = __builtin_bit_cast(uint32_t, f);
    u = (u + 0x7fff + ((u >> 16) & 1)) >> 16;
    return (short)u;
}
__device__ inline float bf2f(short s) {
    return __builtin_bit_cast(float, (uint32_t)(uint16_t)s << 16);
}
__device__ inline void gl_lds16(const void* g, void* l) {
    __builtin_amdgcn_global_load_lds(
        (const __attribute__((address_space(1))) unsigned int*)g,
        (__attribute__((address_space(3))) unsigned int*)l, 16, 0, 0);
}

// ---------------------------------------------------------------------------
// Merged pre-pass: blocks [0,256) do weight stats (float4, atomicAdd);
// blocks [256, 6400) do activation RMSNorm+int8 quant (wave-per-row).
// ---------------------------------------------------------------------------
__global__ __launch_bounds__(256) void pre_kernel(
    const float* __restrict__ qx, const float* __restrict__ kx,
    const float* __restrict__ vx,
    const float* __restrict__ w0, const float* __restrict__ w1,
    const float* __restrict__ w2, const float* __restrict__ w3,
    int8_t* __restrict__ xq01, int8_t* __restrict__ xq2,
    float* __restrict__ dqv, float* __restrict__ stats)
{
    int tid = threadIdx.x, bid = blockIdx.x;
    int lane = tid & 63, wv = tid >> 6;
    if (bid < 256) {
        // ---- weight stats, float4 grid-stride
        int m = bid >> 6;
        const float* w = (m == 0) ? w0 : (m == 1) ? w1 : (m == 2) ? w2 : w3;
        int n4 = ((m == 0) ? 1024 * 1024 : 512 * 1024) >> 2;
        float s = 0.f, sa = 0.f;
        for (int i = (bid & 63) * 256 + tid; i < n4; i += 64 * 256) {
            float4 x = ((const float4*)w)[i];
            s += x.x + x.y + x.z + x.w;
            sa += fabsf(x.x) + fabsf(x.y) + fabsf(x.z) + fabsf(x.w);
        }
#pragma unroll
        for (int o = 32; o; o >>= 1) { s += __shfl_xor(s, o); sa += __shfl_xor(sa, o); }
        __shared__ float ls[4], lsa[4];
        if (!lane) { ls[wv] = s; lsa[wv] = sa; }
        __syncthreads();
        if (!tid) {
            atomicAdd(&stats[2 * m],     ls[0] + ls[1] + ls[2] + ls[3]);
            atomicAdd(&stats[2 * m + 1], lsa[0] + lsa[1] + lsa[2] + lsa[3]);
        }
        return;
    }
    // ---- activation quant, wave-per-row (no barriers)
    int rowi = (bid - 256) * 4 + wv;
    int z = rowi >> 13, r = rowi & (ROWS - 1);
    const float* x = (z == 0) ? qx : (z == 1) ? kx : vx;
    int8_t* xq = (z == 2) ? xq2 : xq01 + (size_t)z * ROWS * E;
    size_t base = (size_t)r * E;
    float4 v[4];
    float ss = 0.f, am = 0.f;
#pragma unroll
    for (int j = 0; j < 4; j++) {
        v[j] = *(const float4*)(x + base + lane * 4 + j * 256);
        ss += v[j].x * v[j].x + v[j].y * v[j].y + v[j].z * v[j].z + v[j].w * v[j].w;
        am = fmaxf(am, fmaxf(fmaxf(fabsf(v[j].x), fabsf(v[j].y)),
                             fmaxf(fabsf(v[j].z), fabsf(v[j].w))));
    }
#pragma unroll
    for (int o = 32; o; o >>= 1) { ss += __shfl_xor(ss, o); am = fmaxf(am, __shfl_xor(am, o)); }
    float rms = rsqrtf(ss * (1.0f / E) + 1e-6f);
    float cl  = fmaxf(am * rms, 1e-5f);
    float kf  = rms * (127.0f / cl);
#pragma unroll
    for (int j = 0; j < 4; j++) {
        int q0 = max(-128, min(127, (int)rintf(v[j].x * kf)));
        int q1 = max(-128, min(127, (int)rintf(v[j].y * kf)));
        int q2 = max(-128, min(127, (int)rintf(v[j].z * kf)));
        int q3 = max(-128, min(127, (int)rintf(v[j].w * kf)));
        uint32_t pk = (uint32_t)(q0 & 0xff) | ((uint32_t)(q1 & 0xff) << 8) |
                      ((uint32_t)(q2 & 0xff) << 16) | ((uint32_t)(q3 & 0xff) << 24);
        *(uint32_t*)(xq + base + lane * 4 + j * 256) = pk;
    }
    if (!lane) dqv[(size_t)z * ROWS + r] = cl * (1.0f / 127.0f);
}

// ---------------------------------------------------------------------------
// Weight ternary quant -> int8 {-1,0,+1} (packed 4-wide)
// ---------------------------------------------------------------------------
__global__ __launch_bounds__(256) void wquant_kernel(
    const float* __restrict__ w0, const float* __restrict__ w1,
    const float* __restrict__ w2, const float* __restrict__ w3,
    int n0, int n1, int n2, int n3, const float* __restrict__ stats,
    int8_t* __restrict__ o0, int8_t* __restrict__ o1,
    int8_t* __restrict__ o2, int8_t* __restrict__ o3)
{
    int m = blockIdx.y;
    const float* w = (m == 0) ? w0 : (m == 1) ? w1 : (m == 2) ? w2 : w3;
    int n = (m == 0) ? n0 : (m == 1) ? n1 : (m == 2) ? n2 : n3;
    int8_t* o = (m == 0) ? o0 : (m == 1) ? o1 : (m == 2) ? o2 : o3;
    float e = stats[2 * m] / (float)n;
    int n4 = n >> 2;
    for (int i = blockIdx.x * 256 + threadIdx.x; i < n4; i += gridDim.x * 256) {
        float4 x = ((const float4*)w)[i];
        int q0 = (x.x > e) - (x.x < e);
        int q1 = (x.y > e) - (x.y < e);
        int q2 = (x.z > e) - (x.z < e);
        int q3 = (x.w > e) - (x.w < e);
        uint32_t pk = (uint32_t)(q0 & 0xff) | ((uint32_t)(q1 & 0xff) << 8) |
                      ((uint32_t)(q2 & 0xff) << 16) | ((uint32_t)(q3 & 0xff) << 24);
        *(uint32_t*)(o + ((size_t)i << 2)) = pk;
    }
}

// ---------------------------------------------------------------------------
// int8 MFMA GEMM body (exact i32 accumulate). 128x128 tile, BK=128 (8 chunk
// positions, XOR (row&7) swizzle), global_load_lds w16, 2 K-halves per stage.
// ---------------------------------------------------------------------------
template <bool F32OUT>
__device__ inline void gemm_body(
    const int8_t* __restrict__ A, const int8_t* __restrict__ W,
    const float* __restrict__ dqv, float sw, void* __restrict__ Cout,
    int O, int K, int8_t* As, int8_t* Ws, size_t row0, size_t c0)
{
    int tid = threadIdx.x;
    int w = tid >> 6, lane = tid & 63;
    int quad = lane >> 4, l15 = lane & 15;
    int mbase = (w & 1) * 64, nbase = (w >> 1) * 64;

    intx4 acc[4][4];
#pragma unroll
    for (int i = 0; i < 4; i++)
#pragma unroll
        for (int j = 0; j < 4; j++) acc[i][j] = (intx4){0, 0, 0, 0};

    const int8_t* Ag[4]; const int8_t* Wg[4]; int8_t* lA[4]; int8_t* lW[4];
#pragma unroll
    for (int t = 0; t < 4; t++) {
        int c = tid + t * 256;
        int row = c >> 3, g = (c & 7) ^ (row & 7);
        Ag[t] = A + (row0 + row) * K + g * 16;
        Wg[t] = W + (c0 + row) * K + g * 16;
        lA[t] = As + c * 16;
        lW[t] = Ws + c * 16;
    }

    for (int kt = 0; kt < K; kt += 128) {
        __syncthreads();
#pragma unroll
        for (int t = 0; t < 4; t++) {
            gl_lds16(Ag[t] + kt, lA[t]);
            gl_lds16(Wg[t] + kt, lW[t]);
        }
        __syncthreads();
#pragma unroll
        for (int kh = 0; kh < 2; kh++) {
            intx4 af[4], bfr[4];
#pragma unroll
            for (int mt = 0; mt < 4; mt++) {
                int row = mbase + mt * 16 + l15;
                int pos = (quad + 4 * kh) ^ (row & 7);
                af[mt] = *(const intx4*)(As + row * 128 + pos * 16);
            }
#pragma unroll
            for (int nt = 0; nt < 4; nt++) {
                int row = nbase + nt * 16 + l15;
                int pos = (quad + 4 * kh) ^ (row & 7);
                bfr[nt] = *(const intx4*)(Ws + row * 128 + pos * 16);
            }
#pragma unroll
            for (int mt = 0; mt < 4; mt++)
#pragma unroll
                for (int nt = 0; nt < 4; nt++)
                    acc[mt][nt] = __builtin_amdgcn_mfma_i32_16x16x64_i8(
                        af[mt], bfr[nt], acc[mt][nt], 0, 0, 0);
        }
    }

#pragma unroll
    for (int mt = 0; mt < 4; mt++) {
#pragma unroll
        for (int r = 0; r < 4; r++) {
            size_t grow = row0 + mbase + mt * 16 + quad * 4 + r;
            float scv = sw * dqv[grow];
#pragma unroll
            for (int nt = 0; nt < 4; nt++) {
                size_t gcol = c0 + nbase + nt * 16 + l15;
                float v = (float)acc[mt][nt][r] * scv;
                if constexpr (F32OUT) ((float*)Cout)[grow * O + gcol] = v;
                else                  ((short*)Cout)[grow * O + gcol] = f2bf(v);
            }
        }
    }
}

// Batched QKV GEMM: flat 1024-block grid (512 q / 256 k / 256 v tiles).
__global__ __launch_bounds__(256) void gemm_qkv(
    const int8_t* __restrict__ xq01, const int8_t* __restrict__ xq2,
    const int8_t* __restrict__ wq_q, const int8_t* __restrict__ wq_k,
    const int8_t* __restrict__ wq_v, const float* __restrict__ dqv,
    const float* __restrict__ stats,
    short* __restrict__ qb, short* __restrict__ kb, short* __restrict__ vb)
{
    __shared__ int8_t As[128 * 128];
    __shared__ int8_t Ws[128 * 128];
    int id = blockIdx.x;
    int z, bx, by;
    if (id < 512)      { z = 0; bx = id & 7; by = id >> 3; }
    else if (id < 768) { z = 1; int t = id - 512; bx = t & 3; by = t >> 2; }
    else               { z = 2; int t = id - 768; bx = t & 3; by = t >> 2; }
    int O = z ? KVE : E;
    const int8_t* A = (z == 0) ? xq01 : (z == 1) ? xq01 + (size_t)ROWS * E : xq2;
    const int8_t* W = (z == 0) ? wq_q : (z == 1) ? wq_k : wq_v;
    short* outp = (z == 0) ? qb : (z == 1) ? kb : vb;
    float sw = stats[2 * z + 1] / (float)(O * E);
    gemm_body<false>(A, W, dqv + (size_t)z * ROWS, sw, outp, O, E, As, Ws,
                     (size_t)by * 128, (size_t)bx * 128);
}

// Output GEMM (fp32 out, K=512)
__global__ __launch_bounds__(256) void gemm_out(
    const int8_t* __restrict__ A, const int8_t* __restrict__ W,
    const float* __restrict__ dqv, const float* __restrict__ stats,
    float* __restrict__ Cout)
{
    __shared__ int8_t As[128 * 128];
    __shared__ int8_t Ws[128 * 128];
    float sw = stats[7] / (float)(E * KVE);
    gemm_body<true>(A, W, dqv, sw, Cout, E, KVE, As, Ws,
                    (size_t)blockIdx.y * 128, (size_t)blockIdx.x * 128);
}

// ---------------------------------------------------------------------------
// MFMA flash attention v12 = R5 wave-split body (occupancy 39.8%, 0 bank
// conflicts, correctness-verified) + R6 XCD swizzle (traffic-verified).
// QBLK=64; 4 waves = (qg,kg) quadrants, per-wave softmax state, final LDS
// merge overlaying dead Ks/Vt. Flat 1024-block grid:
// id = (b<<8)|(q<<3)|(h<<1)|part -> xcd = id&7 = h*2+part; each XCD's 128
// resident blocks share 4 KV slices = 2 MB <= L2 (R6-proven invariant).
// 4 blocks/CU (LDS 34.8KB x4 = 139KB, VGPR 64) = 4 waves/SIMD.
// ---------------------------------------------------------------------------
__global__ __launch_bounds__(256, 4) void attn_mfma(
    const short* __restrict__ qb, const short* __restrict__ kb,
    const short* __restrict__ vb, short* __restrict__ opart,
    float* __restrict__ mlbuf)
{
    // union LDS: staging view {Ks[64][132], Vt[128][68]} = 34304 B;
    // merge view {Om[64][133] fp32 = 34048 B, mlw[128] = 512 B} = 34560 B.
    __shared__ __align__(16) char smem[34816];
    short (*Ks)[132] = (short (*)[132])smem;            // [64][132]
    short (*Vt)[68]  = (short (*)[68])(smem + 16896);   // [128][68]
    float (*Om)[133] = (float (*)[133])smem;            // [64][133]
    float* mlw       = (float*)(smem + 34048);          // [2][32][2]

    int tid = threadIdx.x;
    int w = tid >> 6, lane = tid & 63;
    int l31 = lane & 31, hi = lane >> 5;
    int qg = w & 1, kg = w >> 1;
    // XCD swizzle decode (bijective): id = (b<<8)|(q<<3)|(h<<1)|part
    int id = blockIdx.x;
    int b    = id >> 8;
    int q    = (id >> 3) & 31;
    int h    = (id >> 1) & 3;
    int part = id & 1;
    size_t qrow0 = ((size_t)b * 32 + q) * 64;
    size_t sbase = (size_t)b * SEQ + (size_t)part * KVT;

    int sK = tid >> 2, cK = tid & 3;          // K staging: row, 32-col chunk
    int sV = (tid & 15) * 4, dV = tid >> 4;   // V staging: 4 rows, 8-col chunk

    // ---- prefetch KV tile 0 into registers
    short8 kreg[4], vreg[4];
    {
        const short* ksrc = kb + (sbase + sK) * KVE + h * 128 + cK * 32;
#pragma unroll
        for (int j = 0; j < 4; j++) kreg[j] = *(const short8*)(ksrc + j * 8);
        const short* vsrc = vb + (sbase + sV) * KVE + h * 128 + dV * 8;
#pragma unroll
        for (int j = 0; j < 4; j++) vreg[j] = *(const short8*)(vsrc + j * KVE);
    }

    // ---- Q^T B-frags straight from global: head-pair sum, fold log2e/128
    short8 qfrag[8];
    {
        const short* src = qb + (qrow0 + qg * 32 + l31) * E + h * 256 + hi * 8;
        constexpr float C = 1.44269504089f * (1.0f / 128.0f);
#pragma unroll
        for (int j = 0; j < 8; j++) {
            short8 a  = *(const short8*)(src + j * 16);
            short8 b2 = *(const short8*)(src + j * 16 + 128);
            short8 o;
#pragma unroll
            for (int e = 0; e < 8; e++)
                o[e] = f2bf((bf2f(a[e]) + bf2f(b2[e])) * C);
            qfrag[j] = o;
        }
    }

    floatx16 oacc[4];
#pragma unroll
    for (int dt = 0; dt < 4; dt++)
#pragma unroll
        for (int r = 0; r < 16; r++) oacc[dt][r] = 0.f;
    float m_s = -1e30f, l_s = 0.f;

    for (int st = 0; st < NT; st++) {
        __syncthreads();   // prior readers of Ks/Vt done
        // commit prefetched K tile
#pragma unroll
        for (int j = 0; j < 4; j++)
            *(short8*)&Ks[sK][cK * 32 + j * 8] = kreg[j];
        // commit prefetched V tile (transposed)
#pragma unroll
        for (int i = 0; i < 8; i++) {
            short4v vv = { vreg[0][i], vreg[1][i], vreg[2][i], vreg[3][i] };
            *(short4v*)&Vt[dV * 8 + i][sV] = vv;
        }
        // issue next tile's global loads
        if (st + 1 < NT) {
            size_t srow0 = sbase + (size_t)(st + 1) * 64;
            const short* ksrc = kb + (srow0 + sK) * KVE + h * 128 + cK * 32;
#pragma unroll
            for (int j = 0; j < 4; j++) kreg[j] = *(const short8*)(ksrc + j * 8);
            const short* vsrc = vb + (srow0 + sV) * KVE + h * 128 + dV * 8;
#pragma unroll
            for (int j = 0; j < 4; j++) vreg[j] = *(const short8*)(vsrc + j * KVE);
        }
        __syncthreads();
        // S^T quadrant = K[kg-half] * Q^T[qg-half] (log2 domain)
        floatx16 sc;
#pragma unroll
        for (int r = 0; r < 16; r++) sc[r] = 0.f;
#pragma unroll
        for (int j = 0; j < 8; j++) {
            short8 kf = *(const short8*)&Ks[kg * 32 + l31][j * 16 + hi * 8];
            sc = __builtin_amdgcn_mfma_f32_32x32x16_bf16(kf, qfrag[j], sc, 0, 0, 0);
        }
        // online softmax (base 2) over this wave's 32 keys:
        // lane + lane^32 hold the 32 rows for q-col l31
        float mx = sc[0];
#pragma unroll
        for (int r = 1; r < 16; r++) mx = fmaxf(mx, sc[r]);
        mx = fmaxf(mx, __shfl_xor(mx, 32));
        float pm = fmaxf(m_s, mx);
        // defer-max: only rescale when some lane's max grew by > 8
        if (!__all(pm - m_s <= 8.0f)) {
            float alpha = __builtin_amdgcn_exp2f(m_s - pm);
            m_s = pm;
            l_s *= alpha;
#pragma unroll
            for (int dt = 0; dt < 4; dt++)
#pragma unroll
                for (int r = 0; r < 16; r++) oacc[dt][r] *= alpha;
        }
        float rs = 0.f;
#pragma unroll
        for (int r = 0; r < 16; r++) {
            float p0 = __builtin_amdgcn_exp2f(sc[r] - m_s); sc[r] = p0; rs += p0;
        }
        rs += __shfl_xor(rs, 32);
        l_s += rs;
        // ---- P -> PV B-frags fully in-register:
        // acc reg r of lane(hi) holds key (r&3)+8*(r>>2)+4*hi within the
        // kg-group; pack pairs to bf16 words, permlane32_swap (i, i+2).
        uint32_t w0[8];
#pragma unroll
        for (int i = 0; i < 8; i++) {
            asm("v_cvt_pk_bf16_f32 %0, %1, %2"
                : "=v"(w0[i]) : "v"(sc[2 * i]), "v"(sc[2 * i + 1]));
        }
#pragma unroll
        for (int i = 0; i < 2; i++) {
            { auto r = __builtin_amdgcn_permlane32_swap(w0[i], w0[i + 2], false, false);
              w0[i] = r[0]; w0[i + 2] = r[1]; }
            { auto r = __builtin_amdgcn_permlane32_swap(w0[i + 4], w0[i + 6], false, false);
              w0[i + 4] = r[0]; w0[i + 6] = r[1]; }
        }
        short8 pb[2];
        {
            intx4 t0 = { (int)w0[0], (int)w0[1], (int)w0[2], (int)w0[3] };
            intx4 t1 = { (int)w0[4], (int)w0[5], (int)w0[6], (int)w0[7] };
            pb[0] = __builtin_bit_cast(short8, t0);
            pb[1] = __builtin_bit_cast(short8, t1);
        }
        // PV quadrant: O^T += V^T[.., kg-half] * P^T
#pragma unroll
        for (int dt = 0; dt < 4; dt++)
#pragma unroll
            for (int j = 0; j < 2; j++) {
                short8 vf = *(const short8*)&Vt[dt * 32 + l31][kg * 32 + j * 16 + hi * 8];
                oacc[dt] = __builtin_amdgcn_mfma_f32_32x32x16_bf16(vf, pb[j], oacc[dt], 0, 0, 0);
            }
    }
    // ---- merge kg=0 / kg=1 halves via LDS (overlays dead Ks/Vt), then
    // epilogue: normalized partial O (bf16) + (M, l) [m in log2 domain]
    __syncthreads();   // all Ks/Vt reads done before Om overlay
    if (kg == 1) {
#pragma unroll
        for (int dt = 0; dt < 4; dt++)
#pragma unroll
            for (int r = 0; r < 16; r++) {
                int d = dt * 32 + ((r >> 2) << 3) + hi * 4 + (r & 3);
                Om[qg * 32 + l31][d] = oacc[dt][r];
            }
        if (hi == 0) {
            mlw[qg * 64 + l31 * 2]     = m_s;
            mlw[qg * 64 + l31 * 2 + 1] = l_s;
        }
    }
    __syncthreads();
    if (kg == 0) {
        float m1 = mlw[qg * 64 + l31 * 2];
        float l1 = mlw[qg * 64 + l31 * 2 + 1];
        float M  = fmaxf(m_s, m1);
        float a0 = __builtin_amdgcn_exp2f(m_s - M);
        float a1 = __builtin_amdgcn_exp2f(m1 - M);
        float lm = l_s * a0 + l1 * a1;
        float linv = 1.0f / lm;
        float s0 = a0 * linv, s1 = a1 * linv;
        size_t grow = qrow0 + qg * 32 + l31;
        short* dst = opart + ((size_t)part * ROWS + grow) * KVE + h * 128;
        const float* om = Om[qg * 32 + l31];
#pragma unroll
        for (int dt = 0; dt < 4; dt++)
#pragma unroll
            for (int c = 0; c < 4; c++) {
                int d = dt * 32 + c * 8 + hi * 4;
                short4v o4 = {
                    f2bf(oacc[dt][c * 4 + 0] * s0 + om[d + 0] * s1),
                    f2bf(oacc[dt][c * 4 + 1] * s0 + om[d + 1] * s1),
                    f2bf(oacc[dt][c * 4 + 2] * s0 + om[d + 2] * s1),
                    f2bf(oacc[dt][c * 4 + 3] * s0 + om[d + 3] * s1) };
                *(short4v*)(dst + d) = o4;
            }
        if (hi == 0) {
            float* ml = mlbuf + (((size_t)part * ROWS + grow) * H + h) * 2;
            ml[0] = M;
            ml[1] = lm;
        }
    }
}

// ---------------------------------------------------------------------------
// Partial combine (NSPLIT bf16 partials, base-2 m) + LayerNorm + RMSNorm +
// int8 quant, wave-per-row. Block = 4 waves = 4 rows, grid ROWS/4.
// ---------------------------------------------------------------------------
__global__ __launch_bounds__(256) void ln_combine_kernel(
    const short* __restrict__ opart, const float* __restrict__ mlbuf,
    const float* __restrict__ gamma, const float* __restrict__ beta,
    int8_t* __restrict__ xq, float* __restrict__ dqv)
{
    int lane = threadIdx.x & 63, wv = threadIdx.x >> 6;
    int row = blockIdx.x * 4 + wv;
    float4 y[2];
    float s = 0.f, ss = 0.f;
#pragma unroll
    for (int j = 0; j < 2; j++) {
        int col = lane * 4 + j * 256;
        int h = j * 2 + (lane >> 5);
        float mv[NSPLIT], lv[NSPLIT];
        float M = -1e30f;
#pragma unroll
        for (int p = 0; p < NSPLIT; p++) {
            const float* ml = mlbuf + (((size_t)p * ROWS + row) * H + h) * 2;
            mv[p] = ml[0]; lv[p] = ml[1];
            M = fmaxf(M, mv[p]);
        }
        float wt[NSPLIT], wsum = 0.f;
#pragma unroll
        for (int p = 0; p < NSPLIT; p++) {
            wt[p] = lv[p] * __builtin_amdgcn_exp2f(mv[p] - M);
            wsum += wt[p];
        }
        float winv = 1.0f / wsum;
        float4 vv = { 0.f, 0.f, 0.f, 0.f };
#pragma unroll
        for (int p = 0; p < NSPLIT; p++) {
            short4v o = *(const short4v*)(opart + ((size_t)p * ROWS + row) * KVE + col);
            float wp = wt[p] * winv;
            vv.x += bf2f(o.x) * wp;
            vv.y += bf2f(o.y) * wp;
            vv.z += bf2f(o.z) * wp;
            vv.w += bf2f(o.w) * wp;
        }
        y[j] = vv;
        s += vv.x + vv.y + vv.z + vv.w;
        ss += vv.x * vv.x + vv.y * vv.y + vv.z * vv.z + vv.w * vv.w;
    }
#pragma unroll
    for (int o = 32; o; o >>= 1) { s += __shfl_xor(s, o); ss += __shfl_xor(ss, o); }
    float mu = s * (1.0f / KVE);
    float var = fmaxf(ss * (1.0f / KVE) - mu * mu, 0.0f);
    float inv = rsqrtf(var + 1e-5f);
    float sy = 0.f, am = 0.f;
#pragma unroll
    for (int j = 0; j < 2; j++) {
        int col = lane * 4 + j * 256;
        float4 g = *(const float4*)(gamma + col);
        float4 be = *(const float4*)(beta + col);
        y[j].x = (y[j].x - mu) * inv * g.x + be.x;
        y[j].y = (y[j].y - mu) * inv * g.y + be.y;
        y[j].z = (y[j].z - mu) * inv * g.z + be.z;
        y[j].w = (y[j].w - mu) * inv * g.w + be.w;
        sy += y[j].x * y[j].x + y[j].y * y[j].y + y[j].z * y[j].z + y[j].w * y[j].w;
        am = fmaxf(am, fmaxf(fmaxf(fabsf(y[j].x), fabsf(y[j].y)),
                             fmaxf(fabsf(y[j].z), fabsf(y[j].w))));
    }
#pragma unroll
    for (int o = 32; o; o >>= 1) { sy += __shfl_xor(sy, o); am = fmaxf(am, __shfl_xor(am, o)); }
    float rms = rsqrtf(sy * (1.0f / KVE) + 1e-6f);
    float cl = fmaxf(am * rms, 1e-5f);
    float kf = rms * (127.0f / cl);
#pragma unroll
    for (int j = 0; j < 2; j++) {
        int col = lane * 4 + j * 256;
        int q0 = max(-128, min(127, (int)rintf(y[j].x * kf)));
        int q1 = max(-128, min(127, (int)rintf(y[j].y * kf)));
        int q2 = max(-128, min(127, (int)rintf(y[j].z * kf)));
        int q3 = max(-128, min(127, (int)rintf(y[j].w * kf)));
        uint32_t pk = (uint32_t)(q0 & 0xff) | ((uint32_t)(q1 & 0xff) << 8) |
                      ((uint32_t)(q2 & 0xff) << 16) | ((uint32_t)(q3 & 0xff) << 24);
        *(uint32_t*)(xq + (size_t)row * KVE + col) = pk;
    }
    if (!lane) dqv[row] = cl * (1.0f / 127.0f);
}

// ---------------------------------------------------------------------------
extern "C" void kernel_launch(void* const* d_in, const int* in_sizes, int n_in,
                              void* d_out, int out_size, void* d_ws, size_t ws_size,
                              hipStream_t stream)
{
    const float* query = (const float*)d_in[0];
    const float* key   = (const float*)d_in[1];
    const float* value = (const float*)d_in[2];
    const float* q_w   = (const float*)d_in[3];
    const float* k_w   = (const float*)d_in[4];
    const float* v_w   = (const float*)d_in[5];
    const float* out_w = (const float*)d_in[6];
    const float* ln_g  = (const float*)d_in[7];
    const float* ln_b  = (const float*)d_in[8];
    float* out = (float*)d_out;

    // workspace carve
    char* p = (char*)d_ws;
    float* stats = (float*)p;  p += 256;
    int8_t* wq_q = (int8_t*)p; p += (size_t)1024 * 1024;
    int8_t* wq_k = (int8_t*)p; p += (size_t)512 * 1024;
    int8_t* wq_v = (int8_t*)p; p += (size_t)512 * 1024;
    int8_t* wq_o = (int8_t*)p; p += (size_t)1024 * 512;
    int8_t* xq01 = (int8_t*)p; p += (size_t)2 * ROWS * E;
    float* dqv  = (float*)p;   p += (size_t)3 * ROWS * 4;
    short* qb   = (short*)p;   p += (size_t)ROWS * E * 2;
    short* kb   = (short*)p;   p += (size_t)ROWS * KVE * 2;
    short* vb   = (short*)p;   p += (size_t)ROWS * KVE * 2;
    short* opart = (short*)p;  p += (size_t)NSPLIT * ROWS * KVE * 2;
    float* mlbuf = (float*)p;  p += (size_t)NSPLIT * ROWS * H * 2 * 4;
    // alias (single-stream order makes it sound):
    // xq2 (8 MB, dead before attn writes opart) -> opart (16.8 MB)
    int8_t* xq2 = (int8_t*)opart;
    if ((size_t)(p - (char*)d_ws) > ws_size) return;

    dim3 blk(256);
    hipMemsetAsync(stats, 0, 256, stream);
    pre_kernel<<<dim3(256 + 3 * ROWS / 4), blk, 0, stream>>>(query, key, value,
        q_w, k_w, v_w, out_w, xq01, xq2, dqv, stats);
    wquant_kernel<<<dim3(64, 4), blk, 0, stream>>>(q_w, k_w, v_w, out_w,
        1024 * 1024, 512 * 1024, 512 * 1024, 1024 * 512, stats, wq_q, wq_k, wq_v, wq_o);

    gemm_qkv<<<dim3(1024), blk, 0, stream>>>(xq01, xq2, wq_q, wq_k, wq_v,
        dqv, stats, qb, kb, vb);

    attn_mfma<<<dim3(1024), blk, 0, stream>>>(qb, kb, vb, opart, mlbuf);

    ln_combine_kernel<<<dim3(ROWS / 4), blk, 0, stream>>>(opart, mlbuf,
        ln_g, ln_b, xq01, dqv);
    gemm_out<<<dim3(8, 64), blk, 0, stream>>>(xq01, wq_o, dqv, stats, out);
}

// Round 8
// 372.076 us; speedup vs baseline: 1.0674x; 1.0674x over previous
//
#include <hip/hip_runtime.h>
#include <cstdint>
#include <cstddef>

// Problem constants
constexpr int B_   = 4;
constexpr int SEQ  = 2048;
constexpr int E    = 1024;   // embed dim
constexpr int KVE  = 512;    // kv embed dim
constexpr int H    = 4;      // kv heads
constexpr int ROWS = B_ * SEQ;   // 8192 tokens
constexpr int NSPLIT = 2;        // KV split
constexpr int KVT  = SEQ / NSPLIT;  // 1024 keys per block
constexpr int NT   = KVT / 64;      // 16 tiles of 64 keys

typedef short short8   __attribute__((ext_vector_type(8)));
typedef short short4v  __attribute__((ext_vector_type(4)));
typedef float floatx4  __attribute__((ext_vector_type(4)));
typedef float floatx16 __attribute__((ext_vector_type(16)));
typedef int   intx4    __attribute__((ext_vector_type(4)));

__device__ inline short f2bf(float f) {   // RNE float->bf16
    uint32_t u = __builtin_bit_cast(uint32_t, f);
    u = (u + 0x7fff + ((u >> 16) & 1)) >> 16;
    return (short)u;
}
__device__ inline float bf2f(short s) {
    return __builtin_bit_cast(float, (uint32_t)(uint16_t)s << 16);
}
__device__ inline void gl_lds16(const void* g, void* l) {
    __builtin_amdgcn_global_load_lds(
        (const __attribute__((address_space(1))) unsigned int*)g,
        (__attribute__((address_space(3))) unsigned int*)l, 16, 0, 0);
}

// ---------------------------------------------------------------------------
// Merged pre-pass: blocks [0,256) do weight stats (float4, atomicAdd);
// blocks [256, 6400) do activation RMSNorm+int8 quant (wave-per-row).
// ---------------------------------------------------------------------------
__global__ __launch_bounds__(256) void pre_kernel(
    const float* __restrict__ qx, const float* __restrict__ kx,
    const float* __restrict__ vx,
    const float* __restrict__ w0, const float* __restrict__ w1,
    const float* __restrict__ w2, const float* __restrict__ w3,
    int8_t* __restrict__ xq01, int8_t* __restrict__ xq2,
    float* __restrict__ dqv, float* __restrict__ stats)
{
    int tid = threadIdx.x, bid = blockIdx.x;
    int lane = tid & 63, wv = tid >> 6;
    if (bid < 256) {
        // ---- weight stats, float4 grid-stride
        int m = bid >> 6;
        const float* w = (m == 0) ? w0 : (m == 1) ? w1 : (m == 2) ? w2 : w3;
        int n4 = ((m == 0) ? 1024 * 1024 : 512 * 1024) >> 2;
        float s = 0.f, sa = 0.f;
        for (int i = (bid & 63) * 256 + tid; i < n4; i += 64 * 256) {
            float4 x = ((const float4*)w)[i];
            s += x.x + x.y + x.z + x.w;
            sa += fabsf(x.x) + fabsf(x.y) + fabsf(x.z) + fabsf(x.w);
        }
#pragma unroll
        for (int o = 32; o; o >>= 1) { s += __shfl_xor(s, o); sa += __shfl_xor(sa, o); }
        __shared__ float ls[4], lsa[4];
        if (!lane) { ls[wv] = s; lsa[wv] = sa; }
        __syncthreads();
        if (!tid) {
            atomicAdd(&stats[2 * m],     ls[0] + ls[1] + ls[2] + ls[3]);
            atomicAdd(&stats[2 * m + 1], lsa[0] + lsa[1] + lsa[2] + lsa[3]);
        }
        return;
    }
    // ---- activation quant, wave-per-row (no barriers)
    int rowi = (bid - 256) * 4 + wv;
    int z = rowi >> 13, r = rowi & (ROWS - 1);
    const float* x = (z == 0) ? qx : (z == 1) ? kx : vx;
    int8_t* xq = (z == 2) ? xq2 : xq01 + (size_t)z * ROWS * E;
    size_t base = (size_t)r * E;
    float4 v[4];
    float ss = 0.f, am = 0.f;
#pragma unroll
    for (int j = 0; j < 4; j++) {
        v[j] = *(const float4*)(x + base + lane * 4 + j * 256);
        ss += v[j].x * v[j].x + v[j].y * v[j].y + v[j].z * v[j].z + v[j].w * v[j].w;
        am = fmaxf(am, fmaxf(fmaxf(fabsf(v[j].x), fabsf(v[j].y)),
                             fmaxf(fabsf(v[j].z), fabsf(v[j].w))));
    }
#pragma unroll
    for (int o = 32; o; o >>= 1) { ss += __shfl_xor(ss, o); am = fmaxf(am, __shfl_xor(am, o)); }
    float rms = rsqrtf(ss * (1.0f / E) + 1e-6f);
    float cl  = fmaxf(am * rms, 1e-5f);
    float kf  = rms * (127.0f / cl);
#pragma unroll
    for (int j = 0; j < 4; j++) {
        int q0 = max(-128, min(127, (int)rintf(v[j].x * kf)));
        int q1 = max(-128, min(127, (int)rintf(v[j].y * kf)));
        int q2 = max(-128, min(127, (int)rintf(v[j].z * kf)));
        int q3 = max(-128, min(127, (int)rintf(v[j].w * kf)));
        uint32_t pk = (uint32_t)(q0 & 0xff) | ((uint32_t)(q1 & 0xff) << 8) |
                      ((uint32_t)(q2 & 0xff) << 16) | ((uint32_t)(q3 & 0xff) << 24);
        *(uint32_t*)(xq + base + lane * 4 + j * 256) = pk;
    }
    if (!lane) dqv[(size_t)z * ROWS + r] = cl * (1.0f / 127.0f);
}

// ---------------------------------------------------------------------------
// Weight ternary quant -> int8 {-1,0,+1} (packed 4-wide)
// ---------------------------------------------------------------------------
__global__ __launch_bounds__(256) void wquant_kernel(
    const float* __restrict__ w0, const float* __restrict__ w1,
    const float* __restrict__ w2, const float* __restrict__ w3,
    int n0, int n1, int n2, int n3, const float* __restrict__ stats,
    int8_t* __restrict__ o0, int8_t* __restrict__ o1,
    int8_t* __restrict__ o2, int8_t* __restrict__ o3)
{
    int m = blockIdx.y;
    const float* w = (m == 0) ? w0 : (m == 1) ? w1 : (m == 2) ? w2 : w3;
    int n = (m == 0) ? n0 : (m == 1) ? n1 : (m == 2) ? n2 : n3;
    int8_t* o = (m == 0) ? o0 : (m == 1) ? o1 : (m == 2) ? o2 : o3;
    float e = stats[2 * m] / (float)n;
    int n4 = n >> 2;
    for (int i = blockIdx.x * 256 + threadIdx.x; i < n4; i += gridDim.x * 256) {
        float4 x = ((const float4*)w)[i];
        int q0 = (x.x > e) - (x.x < e);
        int q1 = (x.y > e) - (x.y < e);
        int q2 = (x.z > e) - (x.z < e);
        int q3 = (x.w > e) - (x.w < e);
        uint32_t pk = (uint32_t)(q0 & 0xff) | ((uint32_t)(q1 & 0xff) << 8) |
                      ((uint32_t)(q2 & 0xff) << 16) | ((uint32_t)(q3 & 0xff) << 24);
        *(uint32_t*)(o + ((size_t)i << 2)) = pk;
    }
}

// ---------------------------------------------------------------------------
// int8 MFMA GEMM body (exact i32 accumulate). 128x128 tile, BK=128 (8 chunk
// positions, XOR (row&7) swizzle), global_load_lds w16, 2 K-halves per stage.
// ---------------------------------------------------------------------------
template <bool F32OUT>
__device__ inline void gemm_body(
    const int8_t* __restrict__ A, const int8_t* __restrict__ W,
    const float* __restrict__ dqv, float sw, void* __restrict__ Cout,
    int O, int K, int8_t* As, int8_t* Ws, size_t row0, size_t c0)
{
    int tid = threadIdx.x;
    int w = tid >> 6, lane = tid & 63;
    int quad = lane >> 4, l15 = lane & 15;
    int mbase = (w & 1) * 64, nbase = (w >> 1) * 64;

    intx4 acc[4][4];
#pragma unroll
    for (int i = 0; i < 4; i++)
#pragma unroll
        for (int j = 0; j < 4; j++) acc[i][j] = (intx4){0, 0, 0, 0};

    const int8_t* Ag[4]; const int8_t* Wg[4]; int8_t* lA[4]; int8_t* lW[4];
#pragma unroll
    for (int t = 0; t < 4; t++) {
        int c = tid + t * 256;
        int row = c >> 3, g = (c & 7) ^ (row & 7);
        Ag[t] = A + (row0 + row) * K + g * 16;
        Wg[t] = W + (c0 + row) * K + g * 16;
        lA[t] = As + c * 16;
        lW[t] = Ws + c * 16;
    }

    for (int kt = 0; kt < K; kt += 128) {
        __syncthreads();
#pragma unroll
        for (int t = 0; t < 4; t++) {
            gl_lds16(Ag[t] + kt, lA[t]);
            gl_lds16(Wg[t] + kt, lW[t]);
        }
        __syncthreads();
#pragma unroll
        for (int kh = 0; kh < 2; kh++) {
            intx4 af[4], bfr[4];
#pragma unroll
            for (int mt = 0; mt < 4; mt++) {
                int row = mbase + mt * 16 + l15;
                int pos = (quad + 4 * kh) ^ (row & 7);
                af[mt] = *(const intx4*)(As + row * 128 + pos * 16);
            }
#pragma unroll
            for (int nt = 0; nt < 4; nt++) {
                int row = nbase + nt * 16 + l15;
                int pos = (quad + 4 * kh) ^ (row & 7);
                bfr[nt] = *(const intx4*)(Ws + row * 128 + pos * 16);
            }
#pragma unroll
            for (int mt = 0; mt < 4; mt++)
#pragma unroll
                for (int nt = 0; nt < 4; nt++)
                    acc[mt][nt] = __builtin_amdgcn_mfma_i32_16x16x64_i8(
                        af[mt], bfr[nt], acc[mt][nt], 0, 0, 0);
        }
    }

#pragma unroll
    for (int mt = 0; mt < 4; mt++) {
#pragma unroll
        for (int r = 0; r < 4; r++) {
            size_t grow = row0 + mbase + mt * 16 + quad * 4 + r;
            float scv = sw * dqv[grow];
#pragma unroll
            for (int nt = 0; nt < 4; nt++) {
                size_t gcol = c0 + nbase + nt * 16 + l15;
                float v = (float)acc[mt][nt][r] * scv;
                if constexpr (F32OUT) ((float*)Cout)[grow * O + gcol] = v;
                else                  ((short*)Cout)[grow * O + gcol] = f2bf(v);
            }
        }
    }
}

// Batched QKV GEMM: flat 1024-block grid (512 q / 256 k / 256 v tiles).
__global__ __launch_bounds__(256) void gemm_qkv(
    const int8_t* __restrict__ xq01, const int8_t* __restrict__ xq2,
    const int8_t* __restrict__ wq_q, const int8_t* __restrict__ wq_k,
    const int8_t* __restrict__ wq_v, const float* __restrict__ dqv,
    const float* __restrict__ stats,
    short* __restrict__ qb, short* __restrict__ kb, short* __restrict__ vb)
{
    __shared__ int8_t As[128 * 128];
    __shared__ int8_t Ws[128 * 128];
    int id = blockIdx.x;
    int z, bx, by;
    if (id < 512)      { z = 0; bx = id & 7; by = id >> 3; }
    else if (id < 768) { z = 1; int t = id - 512; bx = t & 3; by = t >> 2; }
    else               { z = 2; int t = id - 768; bx = t & 3; by = t >> 2; }
    int O = z ? KVE : E;
    const int8_t* A = (z == 0) ? xq01 : (z == 1) ? xq01 + (size_t)ROWS * E : xq2;
    const int8_t* W = (z == 0) ? wq_q : (z == 1) ? wq_k : wq_v;
    short* outp = (z == 0) ? qb : (z == 1) ? kb : vb;
    float sw = stats[2 * z + 1] / (float)(O * E);
    gemm_body<false>(A, W, dqv + (size_t)z * ROWS, sw, outp, O, E, As, Ws,
                     (size_t)by * 128, (size_t)bx * 128);
}

// Output GEMM (fp32 out, K=512)
__global__ __launch_bounds__(256) void gemm_out(
    const int8_t* __restrict__ A, const int8_t* __restrict__ W,
    const float* __restrict__ dqv, const float* __restrict__ stats,
    float* __restrict__ Cout)
{
    __shared__ int8_t As[128 * 128];
    __shared__ int8_t Ws[128 * 128];
    float sw = stats[7] / (float)(E * KVE);
    gemm_body<true>(A, W, dqv, sw, Cout, E, KVE, As, Ws,
                    (size_t)blockIdx.y * 128, (size_t)blockIdx.x * 128);
}

// ---------------------------------------------------------------------------
// MFMA flash attention v13: R6's block/slice topology (512 blocks, QBLK=128,
// 16 readers/slice, 2 blocks/CU, XCD swizzle) but 512-thread blocks with
// 8 quadrant-waves (qg 0..3 x kg 0..1, R7-verified numerics) -> 4 waves/SIMD
// at IDENTICAL traffic. Per-wave softmax chain halves (16 exp2/tile).
// f32 LDS merge in two qg-phases (overlays dead Ks/Vt). Tree reductions.
// LDS 35.3 KB x 2 blocks/CU = 70.7 KB.
// ---------------------------------------------------------------------------
__global__ __launch_bounds__(512, 4) void attn_mfma(
    const short* __restrict__ qb, const short* __restrict__ kb,
    const short* __restrict__ vb, short* __restrict__ opart,
    float* __restrict__ mlbuf)
{
    // union LDS: staging {Ks[64][132], Vt[128][68]} = 34304 B;
    // merge (per phase) {Om[64][133] f32 = 34048 B, mlw[2][32][2] = 512 B}.
    __shared__ __align__(16) char smem[35328];
    short (*Ks)[132] = (short (*)[132])smem;            // [64][132]
    short (*Vt)[68]  = (short (*)[68])(smem + 16896);   // [128][68]
    float (*Om)[133] = (float (*)[133])smem;            // [64][133]
    float* mlw       = (float*)(smem + 34048);          // [2][32][2]

    int tid = threadIdx.x;
    int w = tid >> 6, lane = tid & 63;
    int l31 = lane & 31, hi = lane >> 5;
    int qg = w & 3, kg = w >> 2;
    // XCD swizzle decode (bijective, byte-identical to R6):
    // id = (b<<7)|(q<<3)|(h<<1)|part -> xcd = id&7 = h*2+part
    int id = blockIdx.x;
    int b    = id >> 7;
    int q    = (id >> 3) & 15;
    int h    = (id >> 1) & 3;
    int part = id & 1;
    size_t qrow0 = ((size_t)b * 16 + q) * 128;
    size_t sbase = (size_t)b * SEQ + (size_t)part * KVT;

    // staging roles: tid<256 stage V (R6 pattern), tid>=256 stage K (R6 pattern)
    bool doV = tid < 256;
    int t = tid & 255;
    int sV = (t & 15) * 4, dV = t >> 4;   // V: 4 rows, 8-dim chunk
    int sK = t >> 2,  cK = t & 3;         // K: row, 32-col chunk

    // ---- prefetch KV tile 0 into registers
    short8 reg[4];
    if (doV) {
        const short* vsrc = vb + (sbase + sV) * KVE + h * 128 + dV * 8;
#pragma unroll
        for (int j = 0; j < 4; j++) reg[j] = *(const short8*)(vsrc + j * KVE);
    } else {
        const short* ksrc = kb + (sbase + sK) * KVE + h * 128 + cK * 32;
#pragma unroll
        for (int j = 0; j < 4; j++) reg[j] = *(const short8*)(ksrc + j * 8);
    }

    // ---- Q^T B-frags straight from global: head-pair sum, fold log2e/128
    short8 qfrag[8];
    {
        const short* src = qb + (qrow0 + qg * 32 + l31) * E + h * 256 + hi * 8;
        constexpr float C = 1.44269504089f * (1.0f / 128.0f);
#pragma unroll
        for (int j = 0; j < 8; j++) {
            short8 a  = *(const short8*)(src + j * 16);
            short8 b2 = *(const short8*)(src + j * 16 + 128);
            short8 o;
#pragma unroll
            for (int e = 0; e < 8; e++)
                o[e] = f2bf((bf2f(a[e]) + bf2f(b2[e])) * C);
            qfrag[j] = o;
        }
    }

    floatx16 oacc[4];
#pragma unroll
    for (int dt = 0; dt < 4; dt++)
#pragma unroll
        for (int r = 0; r < 16; r++) oacc[dt][r] = 0.f;
    float m_s = -1e30f, l_s = 0.f;

    for (int st = 0; st < NT; st++) {
        __syncthreads();   // prior readers of Ks/Vt done
        if (doV) {
#pragma unroll
            for (int i = 0; i < 8; i++) {
                short4v vv = { reg[0][i], reg[1][i], reg[2][i], reg[3][i] };
                *(short4v*)&Vt[dV * 8 + i][sV] = vv;
            }
        } else {
#pragma unroll
            for (int j = 0; j < 4; j++)
                *(short8*)&Ks[sK][cK * 32 + j * 8] = reg[j];
        }
        // issue next tile's global loads
        if (st + 1 < NT) {
            size_t srow0 = sbase + (size_t)(st + 1) * 64;
            if (doV) {
                const short* vsrc = vb + (srow0 + sV) * KVE + h * 128 + dV * 8;
#pragma unroll
                for (int j = 0; j < 4; j++) reg[j] = *(const short8*)(vsrc + j * KVE);
            } else {
                const short* ksrc = kb + (srow0 + sK) * KVE + h * 128 + cK * 32;
#pragma unroll
                for (int j = 0; j < 4; j++) reg[j] = *(const short8*)(ksrc + j * 8);
            }
        }
        __syncthreads();
        // S^T quadrant = K[kg-half] * Q^T[qg-quarter] (log2 domain)
        floatx16 sc;
#pragma unroll
        for (int r = 0; r < 16; r++) sc[r] = 0.f;
#pragma unroll
        for (int j = 0; j < 8; j++) {
            short8 kf = *(const short8*)&Ks[kg * 32 + l31][j * 16 + hi * 8];
            sc = __builtin_amdgcn_mfma_f32_32x32x16_bf16(kf, qfrag[j], sc, 0, 0, 0);
        }
        // online softmax (base 2), tree max; lane+lane^32 hold the 32 keys
        float x0 = fmaxf(sc[0], sc[1]),  x1 = fmaxf(sc[2], sc[3]);
        float x2 = fmaxf(sc[4], sc[5]),  x3 = fmaxf(sc[6], sc[7]);
        float x4 = fmaxf(sc[8], sc[9]),  x5 = fmaxf(sc[10], sc[11]);
        float x6 = fmaxf(sc[12], sc[13]), x7 = fmaxf(sc[14], sc[15]);
        x0 = fmaxf(x0, x1); x2 = fmaxf(x2, x3); x4 = fmaxf(x4, x5); x6 = fmaxf(x6, x7);
        float mx = fmaxf(fmaxf(x0, x2), fmaxf(x4, x6));
        mx = fmaxf(mx, __shfl_xor(mx, 32));
        float pm = fmaxf(m_s, mx);
        // defer-max: only rescale when some lane's max grew by > 8
        if (!__all(pm - m_s <= 8.0f)) {
            float alpha = __builtin_amdgcn_exp2f(m_s - pm);
            m_s = pm;
            l_s *= alpha;
#pragma unroll
            for (int dt = 0; dt < 4; dt++)
#pragma unroll
                for (int r = 0; r < 16; r++) oacc[dt][r] *= alpha;
        }
#pragma unroll
        for (int r = 0; r < 16; r++) sc[r] = __builtin_amdgcn_exp2f(sc[r] - m_s);
        float rs = (((sc[0] + sc[1]) + (sc[2] + sc[3])) +
                    ((sc[4] + sc[5]) + (sc[6] + sc[7]))) +
                   (((sc[8] + sc[9]) + (sc[10] + sc[11])) +
                    ((sc[12] + sc[13]) + (sc[14] + sc[15])));
        rs += __shfl_xor(rs, 32);
        l_s += rs;
        // ---- P -> PV B-frags fully in-register (R7-verified):
        uint32_t w0[8];
#pragma unroll
        for (int i = 0; i < 8; i++) {
            asm("v_cvt_pk_bf16_f32 %0, %1, %2"
                : "=v"(w0[i]) : "v"(sc[2 * i]), "v"(sc[2 * i + 1]));
        }
#pragma unroll
        for (int i = 0; i < 2; i++) {
            { auto r = __builtin_amdgcn_permlane32_swap(w0[i], w0[i + 2], false, false);
              w0[i] = r[0]; w0[i + 2] = r[1]; }
            { auto r = __builtin_amdgcn_permlane32_swap(w0[i + 4], w0[i + 6], false, false);
              w0[i + 4] = r[0]; w0[i + 6] = r[1]; }
        }
        short8 pb[2];
        {
            intx4 t0 = { (int)w0[0], (int)w0[1], (int)w0[2], (int)w0[3] };
            intx4 t1 = { (int)w0[4], (int)w0[5], (int)w0[6], (int)w0[7] };
            pb[0] = __builtin_bit_cast(short8, t0);
            pb[1] = __builtin_bit_cast(short8, t1);
        }
        // PV quadrant: O^T += V^T[.., kg-half] * P^T
#pragma unroll
        for (int dt = 0; dt < 4; dt++)
#pragma unroll
            for (int j = 0; j < 2; j++) {
                short8 vf = *(const short8*)&Vt[dt * 32 + l31][kg * 32 + j * 16 + hi * 8];
                oacc[dt] = __builtin_amdgcn_mfma_f32_32x32x16_bf16(vf, pb[j], oacc[dt], 0, 0, 0);
            }
    }
    // ---- merge kg halves via LDS (f32, two qg-phases; overlays dead Ks/Vt)
    __syncthreads();   // all Ks/Vt reads done before Om overlay
#pragma unroll
    for (int ph = 0; ph < 2; ph++) {
        if (kg == 1 && (qg >> 1) == ph) {
            int qr = (qg & 1) * 32 + l31;
#pragma unroll
            for (int dt = 0; dt < 4; dt++)
#pragma unroll
                for (int r = 0; r < 16; r++) {
                    int d = dt * 32 + ((r >> 2) << 3) + hi * 4 + (r & 3);
                    Om[qr][d] = oacc[dt][r];
                }
            if (hi == 0) {
                mlw[(qg & 1) * 64 + l31 * 2]     = m_s;
                mlw[(qg & 1) * 64 + l31 * 2 + 1] = l_s;
            }
        }
        __syncthreads();
        if (kg == 0 && (qg >> 1) == ph) {
            int qr = (qg & 1) * 32 + l31;
            float m1 = mlw[(qg & 1) * 64 + l31 * 2];
            float l1 = mlw[(qg & 1) * 64 + l31 * 2 + 1];
            float M  = fmaxf(m_s, m1);
            float a0 = __builtin_amdgcn_exp2f(m_s - M);
            float a1 = __builtin_amdgcn_exp2f(m1 - M);
            float lm = l_s * a0 + l1 * a1;
            float linv = 1.0f / lm;
            float s0 = a0 * linv, s1 = a1 * linv;
            size_t grow = qrow0 + qg * 32 + l31;
            short* dst = opart + ((size_t)part * ROWS + grow) * KVE + h * 128;
            const float* om = Om[qr];
#pragma unroll
            for (int dt = 0; dt < 4; dt++)
#pragma unroll
                for (int c = 0; c < 4; c++) {
                    int d = dt * 32 + c * 8 + hi * 4;
                    short4v o4 = {
                        f2bf(oacc[dt][c * 4 + 0] * s0 + om[d + 0] * s1),
                        f2bf(oacc[dt][c * 4 + 1] * s0 + om[d + 1] * s1),
                        f2bf(oacc[dt][c * 4 + 2] * s0 + om[d + 2] * s1),
                        f2bf(oacc[dt][c * 4 + 3] * s0 + om[d + 3] * s1) };
                    *(short4v*)(dst + d) = o4;
                }
            if (hi == 0) {
                float* ml = mlbuf + (((size_t)part * ROWS + grow) * H + h) * 2;
                ml[0] = M;
                ml[1] = lm;
            }
        }
        __syncthreads();
    }
}

// ---------------------------------------------------------------------------
// Partial combine (NSPLIT bf16 partials, base-2 m) + LayerNorm + RMSNorm +
// int8 quant, wave-per-row. Block = 4 waves = 4 rows, grid ROWS/4.
// ---------------------------------------------------------------------------
__global__ __launch_bounds__(256) void ln_combine_kernel(
    const short* __restrict__ opart, const float* __restrict__ mlbuf,
    const float* __restrict__ gamma, const float* __restrict__ beta,
    int8_t* __restrict__ xq, float* __restrict__ dqv)
{
    int lane = threadIdx.x & 63, wv = threadIdx.x >> 6;
    int row = blockIdx.x * 4 + wv;
    float4 y[2];
    float s = 0.f, ss = 0.f;
#pragma unroll
    for (int j = 0; j < 2; j++) {
        int col = lane * 4 + j * 256;
        int h = j * 2 + (lane >> 5);
        float mv[NSPLIT], lv[NSPLIT];
        float M = -1e30f;
#pragma unroll
        for (int p = 0; p < NSPLIT; p++) {
            const float* ml = mlbuf + (((size_t)p * ROWS + row) * H + h) * 2;
            mv[p] = ml[0]; lv[p] = ml[1];
            M = fmaxf(M, mv[p]);
        }
        float wt[NSPLIT], wsum = 0.f;
#pragma unroll
        for (int p = 0; p < NSPLIT; p++) {
            wt[p] = lv[p] * __builtin_amdgcn_exp2f(mv[p] - M);
            wsum += wt[p];
        }
        float winv = 1.0f / wsum;
        float4 vv = { 0.f, 0.f, 0.f, 0.f };
#pragma unroll
        for (int p = 0; p < NSPLIT; p++) {
            short4v o = *(const short4v*)(opart + ((size_t)p * ROWS + row) * KVE + col);
            float wp = wt[p] * winv;
            vv.x += bf2f(o.x) * wp;
            vv.y += bf2f(o.y) * wp;
            vv.z += bf2f(o.z) * wp;
            vv.w += bf2f(o.w) * wp;
        }
        y[j] = vv;
        s += vv.x + vv.y + vv.z + vv.w;
        ss += vv.x * vv.x + vv.y * vv.y + vv.z * vv.z + vv.w * vv.w;
    }
#pragma unroll
    for (int o = 32; o; o >>= 1) { s += __shfl_xor(s, o); ss += __shfl_xor(ss, o); }
    float mu = s * (1.0f / KVE);
    float var = fmaxf(ss * (1.0f / KVE) - mu * mu, 0.0f);
    float inv = rsqrtf(var + 1e-5f);
    float sy = 0.f, am = 0.f;
#pragma unroll
    for (int j = 0; j < 2; j++) {
        int col = lane * 4 + j * 256;
        float4 g = *(const float4*)(gamma + col);
        float4 be = *(const float4*)(beta + col);
        y[j].x = (y[j].x - mu) * inv * g.x + be.x;
        y[j].y = (y[j].y - mu) * inv * g.y + be.y;
        y[j].z = (y[j].z - mu) * inv * g.z + be.z;
        y[j].w = (y[j].w - mu) * inv * g.w + be.w;
        sy += y[j].x * y[j].x + y[j].y * y[j].y + y[j].z * y[j].z + y[j].w * y[j].w;
        am = fmaxf(am, fmaxf(fmaxf(fabsf(y[j].x), fabsf(y[j].y)),
                             fmaxf(fabsf(y[j].z), fabsf(y[j].w))));
    }
#pragma unroll
    for (int o = 32; o; o >>= 1) { sy += __shfl_xor(sy, o); am = fmaxf(am, __shfl_xor(am, o)); }
    float rms = rsqrtf(sy * (1.0f / KVE) + 1e-6f);
    float cl = fmaxf(am * rms, 1e-5f);
    float kf = rms * (127.0f / cl);
#pragma unroll
    for (int j = 0; j < 2; j++) {
        int col = lane * 4 + j * 256;
        int q0 = max(-128, min(127, (int)rintf(y[j].x * kf)));
        int q1 = max(-128, min(127, (int)rintf(y[j].y * kf)));
        int q2 = max(-128, min(127, (int)rintf(y[j].z * kf)));
        int q3 = max(-128, min(127, (int)rintf(y[j].w * kf)));
        uint32_t pk = (uint32_t)(q0 & 0xff) | ((uint32_t)(q1 & 0xff) << 8) |
                      ((uint32_t)(q2 & 0xff) << 16) | ((uint32_t)(q3 & 0xff) << 24);
        *(uint32_t*)(xq + (size_t)row * KVE + col) = pk;
    }
    if (!lane) dqv[row] = cl * (1.0f / 127.0f);
}

// ---------------------------------------------------------------------------
extern "C" void kernel_launch(void* const* d_in, const int* in_sizes, int n_in,
                              void* d_out, int out_size, void* d_ws, size_t ws_size,
                              hipStream_t stream)
{
    const float* query = (const float*)d_in[0];
    const float* key   = (const float*)d_in[1];
    const float* value = (const float*)d_in[2];
    const float* q_w   = (const float*)d_in[3];
    const float* k_w   = (const float*)d_in[4];
    const float* v_w   = (const float*)d_in[5];
    const float* out_w = (const float*)d_in[6];
    const float* ln_g  = (const float*)d_in[7];
    const float* ln_b  = (const float*)d_in[8];
    float* out = (float*)d_out;

    // workspace carve
    char* p = (char*)d_ws;
    float* stats = (float*)p;  p += 256;
    int8_t* wq_q = (int8_t*)p; p += (size_t)1024 * 1024;
    int8_t* wq_k = (int8_t*)p; p += (size_t)512 * 1024;
    int8_t* wq_v = (int8_t*)p; p += (size_t)512 * 1024;
    int8_t* wq_o = (int8_t*)p; p += (size_t)1024 * 512;
    int8_t* xq01 = (int8_t*)p; p += (size_t)2 * ROWS * E;
    float* dqv  = (float*)p;   p += (size_t)3 * ROWS * 4;
    short* qb   = (short*)p;   p += (size_t)ROWS * E * 2;
    short* kb   = (short*)p;   p += (size_t)ROWS * KVE * 2;
    short* vb   = (short*)p;   p += (size_t)ROWS * KVE * 2;
    short* opart = (short*)p;  p += (size_t)NSPLIT * ROWS * KVE * 2;
    float* mlbuf = (float*)p;  p += (size_t)NSPLIT * ROWS * H * 2 * 4;
    // alias (single-stream order makes it sound):
    // xq2 (8 MB, dead before attn writes opart) -> opart (16.8 MB)
    int8_t* xq2 = (int8_t*)opart;
    if ((size_t)(p - (char*)d_ws) > ws_size) return;

    dim3 blk(256);
    hipMemsetAsync(stats, 0, 256, stream);
    pre_kernel<<<dim3(256 + 3 * ROWS / 4), blk, 0, stream>>>(query, key, value,
        q_w, k_w, v_w, out_w, xq01, xq2, dqv, stats);
    wquant_kernel<<<dim3(64, 4), blk, 0, stream>>>(q_w, k_w, v_w, out_w,
        1024 * 1024, 512 * 1024, 512 * 1024, 1024 * 512, stats, wq_q, wq_k, wq_v, wq_o);

    gemm_qkv<<<dim3(1024), blk, 0, stream>>>(xq01, xq2, wq_q, wq_k, wq_v,
        dqv, stats, qb, kb, vb);

    attn_mfma<<<dim3(512), dim3(512), 0, stream>>>(qb, kb, vb, opart, mlbuf);

    ln_combine_kernel<<<dim3(ROWS / 4), blk, 0, stream>>>(opart, mlbuf,
        ln_g, ln_b, xq01, dqv);
    gemm_out<<<dim3(8, 64), blk, 0, stream>>>(xq01, wq_o, dqv, stats, out);
}

// Round 9
// 248.749 us; speedup vs baseline: 1.5966x; 1.4958x over previous
//
#include <hip/hip_runtime.h>
#include <cstdint>
#include <cstddef>

// Problem constants
constexpr int B_   = 4;
constexpr int SEQ  = 2048;
constexpr int E    = 1024;   // embed dim
constexpr int KVE  = 512;    // kv embed dim
constexpr int H    = 4;      // kv heads
constexpr int ROWS = B_ * SEQ;   // 8192 tokens
constexpr int NSPLIT = 2;        // KV split
constexpr int KVT  = SEQ / NSPLIT;  // 1024 keys per block
constexpr int NT   = KVT / 64;      // 16 tiles of 64 keys

typedef short short8   __attribute__((ext_vector_type(8)));
typedef short short4v  __attribute__((ext_vector_type(4)));
typedef float floatx4  __attribute__((ext_vector_type(4)));
typedef float floatx16 __attribute__((ext_vector_type(16)));
typedef int   intx4    __attribute__((ext_vector_type(4)));

__device__ inline short f2bf(float f) {   // RNE float->bf16
    uint32_t u = __builtin_bit_cast(uint32_t, f);
    u = (u + 0x7fff + ((u >> 16) & 1)) >> 16;
    return (short)u;
}
__device__ inline float bf2f(short s) {
    return __builtin_bit_cast(float, (uint32_t)(uint16_t)s << 16);
}
__device__ inline void gl_lds16(const void* g, void* l) {
    __builtin_amdgcn_global_load_lds(
        (const __attribute__((address_space(1))) unsigned int*)g,
        (__attribute__((address_space(3))) unsigned int*)l, 16, 0, 0);
}

// ---------------------------------------------------------------------------
// Merged pre-pass: blocks [0,256) do weight stats (float4, atomicAdd);
// blocks [256, 6400) do activation RMSNorm+int8 quant (wave-per-row).
// ---------------------------------------------------------------------------
__global__ __launch_bounds__(256) void pre_kernel(
    const float* __restrict__ qx, const float* __restrict__ kx,
    const float* __restrict__ vx,
    const float* __restrict__ w0, const float* __restrict__ w1,
    const float* __restrict__ w2, const float* __restrict__ w3,
    int8_t* __restrict__ xq01, int8_t* __restrict__ xq2,
    float* __restrict__ dqv, float* __restrict__ stats)
{
    int tid = threadIdx.x, bid = blockIdx.x;
    int lane = tid & 63, wv = tid >> 6;
    if (bid < 256) {
        // ---- weight stats, float4 grid-stride
        int m = bid >> 6;
        const float* w = (m == 0) ? w0 : (m == 1) ? w1 : (m == 2) ? w2 : w3;
        int n4 = ((m == 0) ? 1024 * 1024 : 512 * 1024) >> 2;
        float s = 0.f, sa = 0.f;
        for (int i = (bid & 63) * 256 + tid; i < n4; i += 64 * 256) {
            float4 x = ((const float4*)w)[i];
            s += x.x + x.y + x.z + x.w;
            sa += fabsf(x.x) + fabsf(x.y) + fabsf(x.z) + fabsf(x.w);
        }
#pragma unroll
        for (int o = 32; o; o >>= 1) { s += __shfl_xor(s, o); sa += __shfl_xor(sa, o); }
        __shared__ float ls[4], lsa[4];
        if (!lane) { ls[wv] = s; lsa[wv] = sa; }
        __syncthreads();
        if (!tid) {
            atomicAdd(&stats[2 * m],     ls[0] + ls[1] + ls[2] + ls[3]);
            atomicAdd(&stats[2 * m + 1], lsa[0] + lsa[1] + lsa[2] + lsa[3]);
        }
        return;
    }
    // ---- activation quant, wave-per-row (no barriers)
    int rowi = (bid - 256) * 4 + wv;
    int z = rowi >> 13, r = rowi & (ROWS - 1);
    const float* x = (z == 0) ? qx : (z == 1) ? kx : vx;
    int8_t* xq = (z == 2) ? xq2 : xq01 + (size_t)z * ROWS * E;
    size_t base = (size_t)r * E;
    float4 v[4];
    float ss = 0.f, am = 0.f;
#pragma unroll
    for (int j = 0; j < 4; j++) {
        v[j] = *(const float4*)(x + base + lane * 4 + j * 256);
        ss += v[j].x * v[j].x + v[j].y * v[j].y + v[j].z * v[j].z + v[j].w * v[j].w;
        am = fmaxf(am, fmaxf(fmaxf(fabsf(v[j].x), fabsf(v[j].y)),
                             fmaxf(fabsf(v[j].z), fabsf(v[j].w))));
    }
#pragma unroll
    for (int o = 32; o; o >>= 1) { ss += __shfl_xor(ss, o); am = fmaxf(am, __shfl_xor(am, o)); }
    float rms = rsqrtf(ss * (1.0f / E) + 1e-6f);
    float cl  = fmaxf(am * rms, 1e-5f);
    float kf  = rms * (127.0f / cl);
#pragma unroll
    for (int j = 0; j < 4; j++) {
        int q0 = max(-128, min(127, (int)rintf(v[j].x * kf)));
        int q1 = max(-128, min(127, (int)rintf(v[j].y * kf)));
        int q2 = max(-128, min(127, (int)rintf(v[j].z * kf)));
        int q3 = max(-128, min(127, (int)rintf(v[j].w * kf)));
        uint32_t pk = (uint32_t)(q0 & 0xff) | ((uint32_t)(q1 & 0xff) << 8) |
                      ((uint32_t)(q2 & 0xff) << 16) | ((uint32_t)(q3 & 0xff) << 24);
        *(uint32_t*)(xq + base + lane * 4 + j * 256) = pk;
    }
    if (!lane) dqv[(size_t)z * ROWS + r] = cl * (1.0f / 127.0f);
}

// ---------------------------------------------------------------------------
// Weight ternary quant -> int8 {-1,0,+1} (packed 4-wide).
// m==4: head-pair-summed Q weights: wqsum[o][k] = sign(w[r1]-e)+sign(w[r2]-e)
// where o = h*128+d, r1 = h*256+d, r2 = r1+128 (values in [-2,2], int8).
// ---------------------------------------------------------------------------
__global__ __launch_bounds__(256) void wquant_kernel(
    const float* __restrict__ w0, const float* __restrict__ w1,
    const float* __restrict__ w2, const float* __restrict__ w3,
    int n0, int n1, int n2, int n3, const float* __restrict__ stats,
    int8_t* __restrict__ o0, int8_t* __restrict__ o1,
    int8_t* __restrict__ o2, int8_t* __restrict__ o3,
    int8_t* __restrict__ oqs)
{
    int m = blockIdx.y;
    if (m == 4) {
        // summed Q weights from w0
        float e = stats[0] / (float)(1024 * 1024);
        int n4 = (512 * 1024) >> 2;   // float4 count of output
        for (int i = blockIdx.x * 256 + threadIdx.x; i < n4; i += gridDim.x * 256) {
            int o = i >> 8;           // output row [0,512)
            int k4 = i & 255;         // float4 col within row
            int r1 = ((o >> 7) * 256 + (o & 127));
            int b1 = r1 * 256 + k4, b2 = b1 + 128 * 256;
            float4 x1 = ((const float4*)w0)[b1];
            float4 x2 = ((const float4*)w0)[b2];
            int q0 = ((x1.x > e) - (x1.x < e)) + ((x2.x > e) - (x2.x < e));
            int q1 = ((x1.y > e) - (x1.y < e)) + ((x2.y > e) - (x2.y < e));
            int q2 = ((x1.z > e) - (x1.z < e)) + ((x2.z > e) - (x2.z < e));
            int q3 = ((x1.w > e) - (x1.w < e)) + ((x2.w > e) - (x2.w < e));
            uint32_t pk = (uint32_t)(q0 & 0xff) | ((uint32_t)(q1 & 0xff) << 8) |
                          ((uint32_t)(q2 & 0xff) << 16) | ((uint32_t)(q3 & 0xff) << 24);
            *(uint32_t*)(oqs + ((size_t)i << 2)) = pk;
        }
        return;
    }
    const float* w = (m == 0) ? w0 : (m == 1) ? w1 : (m == 2) ? w2 : w3;
    int n = (m == 0) ? n0 : (m == 1) ? n1 : (m == 2) ? n2 : n3;
    int8_t* o = (m == 0) ? o0 : (m == 1) ? o1 : (m == 2) ? o2 : o3;
    float e = stats[2 * m] / (float)n;
    int n4 = n >> 2;
    for (int i = blockIdx.x * 256 + threadIdx.x; i < n4; i += gridDim.x * 256) {
        float4 x = ((const float4*)w)[i];
        int q0 = (x.x > e) - (x.x < e);
        int q1 = (x.y > e) - (x.y < e);
        int q2 = (x.z > e) - (x.z < e);
        int q3 = (x.w > e) - (x.w < e);
        uint32_t pk = (uint32_t)(q0 & 0xff) | ((uint32_t)(q1 & 0xff) << 8) |
                      ((uint32_t)(q2 & 0xff) << 16) | ((uint32_t)(q3 & 0xff) << 24);
        *(uint32_t*)(o + ((size_t)i << 2)) = pk;
    }
}

// ---------------------------------------------------------------------------
// int8 MFMA GEMM body (exact i32 accumulate). 128x128 tile, BK=128 (8 chunk
// positions, XOR (row&7) swizzle), global_load_lds w16, 2 K-halves per stage.
// ---------------------------------------------------------------------------
template <bool F32OUT>
__device__ inline void gemm_body(
    const int8_t* __restrict__ A, const int8_t* __restrict__ W,
    const float* __restrict__ dqv, float sw, void* __restrict__ Cout,
    int O, int K, int8_t* As, int8_t* Ws, size_t row0, size_t c0)
{
    int tid = threadIdx.x;
    int w = tid >> 6, lane = tid & 63;
    int quad = lane >> 4, l15 = lane & 15;
    int mbase = (w & 1) * 64, nbase = (w >> 1) * 64;

    intx4 acc[4][4];
#pragma unroll
    for (int i = 0; i < 4; i++)
#pragma unroll
        for (int j = 0; j < 4; j++) acc[i][j] = (intx4){0, 0, 0, 0};

    const int8_t* Ag[4]; const int8_t* Wg[4]; int8_t* lA[4]; int8_t* lW[4];
#pragma unroll
    for (int t = 0; t < 4; t++) {
        int c = tid + t * 256;
        int row = c >> 3, g = (c & 7) ^ (row & 7);
        Ag[t] = A + (row0 + row) * K + g * 16;
        Wg[t] = W + (c0 + row) * K + g * 16;
        lA[t] = As + c * 16;
        lW[t] = Ws + c * 16;
    }

    for (int kt = 0; kt < K; kt += 128) {
        __syncthreads();
#pragma unroll
        for (int t = 0; t < 4; t++) {
            gl_lds16(Ag[t] + kt, lA[t]);
            gl_lds16(Wg[t] + kt, lW[t]);
        }
        __syncthreads();
#pragma unroll
        for (int kh = 0; kh < 2; kh++) {
            intx4 af[4], bfr[4];
#pragma unroll
            for (int mt = 0; mt < 4; mt++) {
                int row = mbase + mt * 16 + l15;
                int pos = (quad + 4 * kh) ^ (row & 7);
                af[mt] = *(const intx4*)(As + row * 128 + pos * 16);
            }
#pragma unroll
            for (int nt = 0; nt < 4; nt++) {
                int row = nbase + nt * 16 + l15;
                int pos = (quad + 4 * kh) ^ (row & 7);
                bfr[nt] = *(const intx4*)(Ws + row * 128 + pos * 16);
            }
#pragma unroll
            for (int mt = 0; mt < 4; mt++)
#pragma unroll
                for (int nt = 0; nt < 4; nt++)
                    acc[mt][nt] = __builtin_amdgcn_mfma_i32_16x16x64_i8(
                        af[mt], bfr[nt], acc[mt][nt], 0, 0, 0);
        }
    }

#pragma unroll
    for (int mt = 0; mt < 4; mt++) {
#pragma unroll
        for (int r = 0; r < 4; r++) {
            size_t grow = row0 + mbase + mt * 16 + quad * 4 + r;
            float scv = sw * dqv[grow];
#pragma unroll
            for (int nt = 0; nt < 4; nt++) {
                size_t gcol = c0 + nbase + nt * 16 + l15;
                float v = (float)acc[mt][nt][r] * scv;
                if constexpr (F32OUT) ((float*)Cout)[grow * O + gcol] = v;
                else                  ((short*)Cout)[grow * O + gcol] = f2bf(v);
            }
        }
    }
}

// Batched QKV GEMM: flat 768-block grid (256 qs / 256 k / 256 v tiles).
// Q-GEMM uses head-pair-summed weights (O=512) and folds log2e/128 into the
// dequant scale -> qs is directly attn's Q operand (no per-wave prep).
__global__ __launch_bounds__(256) void gemm_qkv(
    const int8_t* __restrict__ xq01, const int8_t* __restrict__ xq2,
    const int8_t* __restrict__ wq_qs, const int8_t* __restrict__ wq_k,
    const int8_t* __restrict__ wq_v, const float* __restrict__ dqv,
    const float* __restrict__ stats,
    short* __restrict__ qs, short* __restrict__ kb, short* __restrict__ vb)
{
    __shared__ int8_t As[128 * 128];
    __shared__ int8_t Ws[128 * 128];
    int id = blockIdx.x;
    int z = id >> 8;               // 0: qsum, 1: k, 2: v (256 blocks each)
    int t = id & 255;
    int bx = t & 3, by = t >> 2;   // 4 col-tiles x 64 row-tiles
    const int8_t* A = (z == 0) ? xq01 : (z == 1) ? xq01 + (size_t)ROWS * E : xq2;
    const int8_t* W = (z == 0) ? wq_qs : (z == 1) ? wq_k : wq_v;
    short* outp = (z == 0) ? qs : (z == 1) ? kb : vb;
    float sw = (z == 0)
        ? stats[1] / (float)(E * E) * (1.44269504089f / 128.0f)
        : stats[2 * z + 1] / (float)(KVE * E);
    gemm_body<false>(A, W, dqv + (size_t)z * ROWS, sw, outp, KVE, E, As, Ws,
                     (size_t)by * 128, (size_t)bx * 128);
}

// Output GEMM (fp32 out, K=512)
__global__ __launch_bounds__(256) void gemm_out(
    const int8_t* __restrict__ A, const int8_t* __restrict__ W,
    const float* __restrict__ dqv, const float* __restrict__ stats,
    float* __restrict__ Cout)
{
    __shared__ int8_t As[128 * 128];
    __shared__ int8_t Ws[128 * 128];
    float sw = stats[7] / (float)(E * KVE);
    gemm_body<true>(A, W, dqv, sw, Cout, E, KVE, As, Ws,
                    (size_t)blockIdx.y * 128, (size_t)blockIdx.x * 128);
}

// ---------------------------------------------------------------------------
// MFMA flash attention v14: R6's verified body (58.8us, low-traffic) with Q
// loaded directly from the summed-Q GEMM output (no per-wave prep).
// Flat 512-block grid; id = (b<<7)|(q<<3)|(h<<1)|part -> xcd = id&7: each
// XCD's resident blocks share 4 KV slices = 2 MB <= L2 (R6-verified).
// Keeps: in-reg P (cvt_pk+permlane), log2 softmax, defer-max (THR=8),
// no setprio, NSPLIT=2. LDS 34.3 KB.
// ---------------------------------------------------------------------------
__global__ __launch_bounds__(256, 2) void attn_mfma(
    const short* __restrict__ qs, const short* __restrict__ kb,
    const short* __restrict__ vb, short* __restrict__ opart,
    float* __restrict__ mlbuf)
{
    __shared__ short Ks[64][132];
    __shared__ short Vt[128][68];
    int tid = threadIdx.x;
    int w = tid >> 6, lane = tid & 63;
    int l31 = lane & 31, hi = lane >> 5;
    // XCD swizzle decode (bijective): id = (b<<7)|(q<<3)|(h<<1)|part
    int id = blockIdx.x;
    int b    = id >> 7;
    int q    = (id >> 3) & 15;
    int h    = (id >> 1) & 3;
    int part = id & 1;
    size_t qrow0 = ((size_t)b * 16 + q) * 128;
    size_t sbase = (size_t)b * SEQ + (size_t)part * KVT;

    int sK = tid >> 2, cK = tid & 3;          // K staging: row, 32-col chunk
    int sV = (tid & 15) * 4, dV = tid >> 4;   // V staging: 4 rows, 8-col chunk

    // ---- prefetch KV tile 0 into registers
    short8 kreg[4], vreg[4];
    {
        const short* ksrc = kb + (sbase + sK) * KVE + h * 128 + cK * 32;
#pragma unroll
        for (int j = 0; j < 4; j++) kreg[j] = *(const short8*)(ksrc + j * 8);
        const short* vsrc = vb + (sbase + sV) * KVE + h * 128 + dV * 8;
#pragma unroll
        for (int j = 0; j < 4; j++) vreg[j] = *(const short8*)(vsrc + j * KVE);
    }

    // ---- Q^T B-frags: head-pair sum + log2e/128 already folded by gemm_qkv
    short8 qfrag[8];
    {
        const short* src = qs + (qrow0 + w * 32 + l31) * KVE + h * 128 + hi * 8;
#pragma unroll
        for (int j = 0; j < 8; j++) qfrag[j] = *(const short8*)(src + j * 16);
    }

    floatx16 oacc[4];
#pragma unroll
    for (int dt = 0; dt < 4; dt++)
#pragma unroll
        for (int r = 0; r < 16; r++) oacc[dt][r] = 0.f;
    float m_s = -1e30f, l_s = 0.f;

    for (int st = 0; st < NT; st++) {
        __syncthreads();   // prior readers of Ks/Vt done
        // commit prefetched K tile
#pragma unroll
        for (int j = 0; j < 4; j++)
            *(short8*)&Ks[sK][cK * 32 + j * 8] = kreg[j];
        // commit prefetched V tile (transposed)
#pragma unroll
        for (int i = 0; i < 8; i++) {
            short4v vv = { vreg[0][i], vreg[1][i], vreg[2][i], vreg[3][i] };
            *(short4v*)&Vt[dV * 8 + i][sV] = vv;
        }
        // issue next tile's global loads
        if (st + 1 < NT) {
            size_t srow0 = sbase + (size_t)(st + 1) * 64;
            const short* ksrc = kb + (srow0 + sK) * KVE + h * 128 + cK * 32;
#pragma unroll
            for (int j = 0; j < 4; j++) kreg[j] = *(const short8*)(ksrc + j * 8);
            const short* vsrc = vb + (srow0 + sV) * KVE + h * 128 + dV * 8;
#pragma unroll
            for (int j = 0; j < 4; j++) vreg[j] = *(const short8*)(vsrc + j * KVE);
        }
        __syncthreads();
        // S^T = K * Q^T (log2 domain): keys 0-31 and 32-63 x 32 q-cols
        floatx16 sc0, sc1;
#pragma unroll
        for (int r = 0; r < 16; r++) { sc0[r] = 0.f; sc1[r] = 0.f; }
#pragma unroll
        for (int j = 0; j < 8; j++) {
            short8 kf0 = *(const short8*)&Ks[l31][j * 16 + hi * 8];
            short8 kf1 = *(const short8*)&Ks[32 + l31][j * 16 + hi * 8];
            sc0 = __builtin_amdgcn_mfma_f32_32x32x16_bf16(kf0, qfrag[j], sc0, 0, 0, 0);
            sc1 = __builtin_amdgcn_mfma_f32_32x32x16_bf16(kf1, qfrag[j], sc1, 0, 0, 0);
        }
        // online softmax (base 2): lane + lane^32 hold all 64 keys for this q
        float mx = sc0[0];
#pragma unroll
        for (int r = 0; r < 16; r++) mx = fmaxf(mx, fmaxf(sc0[r], sc1[r]));
        mx = fmaxf(mx, __shfl_xor(mx, 32));
        float pm = fmaxf(m_s, mx);
        // defer-max: only rescale when some lane's max grew by > 8 (2^8 headroom)
        if (!__all(pm - m_s <= 8.0f)) {
            float alpha = __builtin_amdgcn_exp2f(m_s - pm);
            m_s = pm;
            l_s *= alpha;
#pragma unroll
            for (int dt = 0; dt < 4; dt++)
#pragma unroll
                for (int r = 0; r < 16; r++) oacc[dt][r] *= alpha;
        }
        float rs = 0.f;
#pragma unroll
        for (int r = 0; r < 16; r++) {
            float p0 = __builtin_amdgcn_exp2f(sc0[r] - m_s); sc0[r] = p0; rs += p0;
            float p1 = __builtin_amdgcn_exp2f(sc1[r] - m_s); sc1[r] = p1; rs += p1;
        }
        rs += __shfl_xor(rs, 32);
        l_s += rs;
        // ---- P -> PV B-frags fully in-register (A/B-verified R1 vs R2):
        // acc reg r of lane(hi) holds key (r&3)+8*(r>>2)+4*hi; pack pairs to
        // bf16 words, then permlane32_swap pairs (i, i+2) to give each lane
        // the key block hi*8..hi*8+7 it needs as B operand.
        uint32_t w0[8], w1[8];
#pragma unroll
        for (int i = 0; i < 8; i++) {
            asm("v_cvt_pk_bf16_f32 %0, %1, %2"
                : "=v"(w0[i]) : "v"(sc0[2 * i]), "v"(sc0[2 * i + 1]));
            asm("v_cvt_pk_bf16_f32 %0, %1, %2"
                : "=v"(w1[i]) : "v"(sc1[2 * i]), "v"(sc1[2 * i + 1]));
        }
#pragma unroll
        for (int i = 0; i < 2; i++) {
            { auto r = __builtin_amdgcn_permlane32_swap(w0[i], w0[i + 2], false, false);
              w0[i] = r[0]; w0[i + 2] = r[1]; }
            { auto r = __builtin_amdgcn_permlane32_swap(w0[i + 4], w0[i + 6], false, false);
              w0[i + 4] = r[0]; w0[i + 6] = r[1]; }
            { auto r = __builtin_amdgcn_permlane32_swap(w1[i], w1[i + 2], false, false);
              w1[i] = r[0]; w1[i + 2] = r[1]; }
            { auto r = __builtin_amdgcn_permlane32_swap(w1[i + 4], w1[i + 6], false, false);
              w1[i + 4] = r[0]; w1[i + 6] = r[1]; }
        }
        short8 pb[4];
        {
            intx4 t0 = { (int)w0[0], (int)w0[1], (int)w0[2], (int)w0[3] };
            intx4 t1 = { (int)w0[4], (int)w0[5], (int)w0[6], (int)w0[7] };
            intx4 t2 = { (int)w1[0], (int)w1[1], (int)w1[2], (int)w1[3] };
            intx4 t3 = { (int)w1[4], (int)w1[5], (int)w1[6], (int)w1[7] };
            pb[0] = __builtin_bit_cast(short8, t0);
            pb[1] = __builtin_bit_cast(short8, t1);
            pb[2] = __builtin_bit_cast(short8, t2);
            pb[3] = __builtin_bit_cast(short8, t3);
        }
        // PV: O^T = V^T * P^T
#pragma unroll
        for (int dt = 0; dt < 4; dt++)
#pragma unroll
            for (int j = 0; j < 4; j++) {
                short8 vf = *(const short8*)&Vt[dt * 32 + l31][j * 16 + hi * 8];
                oacc[dt] = __builtin_amdgcn_mfma_f32_32x32x16_bf16(vf, pb[j], oacc[dt], 0, 0, 0);
            }
    }
    // epilogue: normalized partial O (bf16) + (m,l)  [m in log2 domain]
    {
        float inv = 1.0f / l_s;
        size_t grow = qrow0 + w * 32 + l31;
        short* dst = opart + ((size_t)part * ROWS + grow) * KVE + h * 128;
#pragma unroll
        for (int dt = 0; dt < 4; dt++)
#pragma unroll
            for (int c = 0; c < 4; c++) {
                short4v o4 = { f2bf(oacc[dt][c * 4] * inv),
                               f2bf(oacc[dt][c * 4 + 1] * inv),
                               f2bf(oacc[dt][c * 4 + 2] * inv),
                               f2bf(oacc[dt][c * 4 + 3] * inv) };
                *(short4v*)(dst + dt * 32 + c * 8 + hi * 4) = o4;
            }
        if (hi == 0) {
            float* ml = mlbuf + (((size_t)part * ROWS + grow) * H + h) * 2;
            ml[0] = m_s;
            ml[1] = l_s;
        }
    }
}

// ---------------------------------------------------------------------------
// Partial combine (NSPLIT bf16 partials, base-2 m) + LayerNorm + RMSNorm +
// int8 quant, wave-per-row. Block = 4 waves = 4 rows, grid ROWS/4.
// ---------------------------------------------------------------------------
__global__ __launch_bounds__(256) void ln_combine_kernel(
    const short* __restrict__ opart, const float* __restrict__ mlbuf,
    const float* __restrict__ gamma, const float* __restrict__ beta,
    int8_t* __restrict__ xq, float* __restrict__ dqv)
{
    int lane = threadIdx.x & 63, wv = threadIdx.x >> 6;
    int row = blockIdx.x * 4 + wv;
    float4 y[2];
    float s = 0.f, ss = 0.f;
#pragma unroll
    for (int j = 0; j < 2; j++) {
        int col = lane * 4 + j * 256;
        int h = j * 2 + (lane >> 5);
        float mv[NSPLIT], lv[NSPLIT];
        float M = -1e30f;
#pragma unroll
        for (int p = 0; p < NSPLIT; p++) {
            const float* ml = mlbuf + (((size_t)p * ROWS + row) * H + h) * 2;
            mv[p] = ml[0]; lv[p] = ml[1];
            M = fmaxf(M, mv[p]);
        }
        float wt[NSPLIT], wsum = 0.f;
#pragma unroll
        for (int p = 0; p < NSPLIT; p++) {
            wt[p] = lv[p] * __builtin_amdgcn_exp2f(mv[p] - M);
            wsum += wt[p];
        }
        float winv = 1.0f / wsum;
        float4 vv = { 0.f, 0.f, 0.f, 0.f };
#pragma unroll
        for (int p = 0; p < NSPLIT; p++) {
            short4v o = *(const short4v*)(opart + ((size_t)p * ROWS + row) * KVE + col);
            float wp = wt[p] * winv;
            vv.x += bf2f(o.x) * wp;
            vv.y += bf2f(o.y) * wp;
            vv.z += bf2f(o.z) * wp;
            vv.w += bf2f(o.w) * wp;
        }
        y[j] = vv;
        s += vv.x + vv.y + vv.z + vv.w;
        ss += vv.x * vv.x + vv.y * vv.y + vv.z * vv.z + vv.w * vv.w;
    }
#pragma unroll
    for (int o = 32; o; o >>= 1) { s += __shfl_xor(s, o); ss += __shfl_xor(ss, o); }
    float mu = s * (1.0f / KVE);
    float var = fmaxf(ss * (1.0f / KVE) - mu * mu, 0.0f);
    float inv = rsqrtf(var + 1e-5f);
    float sy = 0.f, am = 0.f;
#pragma unroll
    for (int j = 0; j < 2; j++) {
        int col = lane * 4 + j * 256;
        float4 g = *(const float4*)(gamma + col);
        float4 be = *(const float4*)(beta + col);
        y[j].x = (y[j].x - mu) * inv * g.x + be.x;
        y[j].y = (y[j].y - mu) * inv * g.y + be.y;
        y[j].z = (y[j].z - mu) * inv * g.z + be.z;
        y[j].w = (y[j].w - mu) * inv * g.w + be.w;
        sy += y[j].x * y[j].x + y[j].y * y[j].y + y[j].z * y[j].z + y[j].w * y[j].w;
        am = fmaxf(am, fmaxf(fmaxf(fabsf(y[j].x), fabsf(y[j].y)),
                             fmaxf(fabsf(y[j].z), fabsf(y[j].w))));
    }
#pragma unroll
    for (int o = 32; o; o >>= 1) { sy += __shfl_xor(sy, o); am = fmaxf(am, __shfl_xor(am, o)); }
    float rms = rsqrtf(sy * (1.0f / KVE) + 1e-6f);
    float cl = fmaxf(am * rms, 1e-5f);
    float kf = rms * (127.0f / cl);
#pragma unroll
    for (int j = 0; j < 2; j++) {
        int col = lane * 4 + j * 256;
        int q0 = max(-128, min(127, (int)rintf(y[j].x * kf)));
        int q1 = max(-128, min(127, (int)rintf(y[j].y * kf)));
        int q2 = max(-128, min(127, (int)rintf(y[j].z * kf)));
        int q3 = max(-128, min(127, (int)rintf(y[j].w * kf)));
        uint32_t pk = (uint32_t)(q0 & 0xff) | ((uint32_t)(q1 & 0xff) << 8) |
                      ((uint32_t)(q2 & 0xff) << 16) | ((uint32_t)(q3 & 0xff) << 24);
        *(uint32_t*)(xq + (size_t)row * KVE + col) = pk;
    }
    if (!lane) dqv[row] = cl * (1.0f / 127.0f);
}

// ---------------------------------------------------------------------------
extern "C" void kernel_launch(void* const* d_in, const int* in_sizes, int n_in,
                              void* d_out, int out_size, void* d_ws, size_t ws_size,
                              hipStream_t stream)
{
    const float* query = (const float*)d_in[0];
    const float* key   = (const float*)d_in[1];
    const float* value = (const float*)d_in[2];
    const float* q_w   = (const float*)d_in[3];
    const float* k_w   = (const float*)d_in[4];
    const float* v_w   = (const float*)d_in[5];
    const float* out_w = (const float*)d_in[6];
    const float* ln_g  = (const float*)d_in[7];
    const float* ln_b  = (const float*)d_in[8];
    float* out = (float*)d_out;

    // workspace carve
    char* p = (char*)d_ws;
    float* stats = (float*)p;  p += 256;
    int8_t* wq_q = (int8_t*)p; p += (size_t)1024 * 1024;
    int8_t* wq_k = (int8_t*)p; p += (size_t)512 * 1024;
    int8_t* wq_v = (int8_t*)p; p += (size_t)512 * 1024;
    int8_t* wq_o = (int8_t*)p; p += (size_t)1024 * 512;
    int8_t* wq_qs = (int8_t*)p; p += (size_t)512 * 1024;   // summed Q weights
    int8_t* xq01 = (int8_t*)p; p += (size_t)2 * ROWS * E;
    float* dqv  = (float*)p;   p += (size_t)3 * ROWS * 4;
    short* qs   = (short*)p;   p += (size_t)ROWS * KVE * 2;  // summed Q (bf16)
    short* kb   = (short*)p;   p += (size_t)ROWS * KVE * 2;
    short* vb   = (short*)p;   p += (size_t)ROWS * KVE * 2;
    short* opart = (short*)p;  p += (size_t)NSPLIT * ROWS * KVE * 2;
    float* mlbuf = (float*)p;  p += (size_t)NSPLIT * ROWS * H * 2 * 4;
    // alias (single-stream order makes it sound):
    // xq2 (8 MB, dead before attn writes opart) -> opart (16.8 MB)
    int8_t* xq2 = (int8_t*)opart;
    if ((size_t)(p - (char*)d_ws) > ws_size) return;

    dim3 blk(256);
    hipMemsetAsync(stats, 0, 256, stream);
    pre_kernel<<<dim3(256 + 3 * ROWS / 4), blk, 0, stream>>>(query, key, value,
        q_w, k_w, v_w, out_w, xq01, xq2, dqv, stats);
    wquant_kernel<<<dim3(64, 5), blk, 0, stream>>>(q_w, k_w, v_w, out_w,
        1024 * 1024, 512 * 1024, 512 * 1024, 1024 * 512, stats,
        wq_q, wq_k, wq_v, wq_o, wq_qs);

    gemm_qkv<<<dim3(768), blk, 0, stream>>>(xq01, xq2, wq_qs, wq_k, wq_v,
        dqv, stats, qs, kb, vb);

    attn_mfma<<<dim3(512), blk, 0, stream>>>(qs, kb, vb, opart, mlbuf);

    ln_combine_kernel<<<dim3(ROWS / 4), blk, 0, stream>>>(opart, mlbuf,
        ln_g, ln_b, xq01, dqv);
    gemm_out<<<dim3(8, 64), blk, 0, stream>>>(xq01, wq_o, dqv, stats, out);
}